// Round 5
// baseline (107.205 us; speedup 1.0000x reference)
//
#include <hip/hip_runtime.h>
#include <hip/hip_bf16.h>

typedef __bf16 bf16x8 __attribute__((ext_vector_type(8)));
typedef float  f32x4  __attribute__((ext_vector_type(4)));
typedef unsigned short us4 __attribute__((ext_vector_type(4)));

#define MFMA16(a, b, c) __builtin_amdgcn_mfma_f32_16x16x32_bf16((a), (b), (c), 0, 0, 0)

constexpr int JJ     = 24;
constexpr int CC     = 64;
constexpr int ROW    = JJ * CC;    // 1536 floats per batch matrix
constexpr int WAVES  = 4;          // 256 threads/block
constexpr int BPW    = 16;         // batches per wave
constexpr int BLOCKS = 16384 / (WAVES * BPW);   // 256 -> 1 block/CU
constexpr int WPITCH = 40;         // padded pitch (bf16) for weights & PT: 80B rows -> 2-way banks

__device__ __forceinline__ void gld16(const float* g, float* l) {
    // direct global->LDS, dwordx4: LDS dst = uniform base + lane*16B; global src per-lane
    __builtin_amdgcn_global_load_lds((const __attribute__((address_space(1))) void*)g,
                                     (__attribute__((address_space(3))) void*)l, 16, 0, 0);
}

__global__ __launch_bounds__(256, 1) void n2e_kernel(
    const float* __restrict__ node, const float* __restrict__ edge,
    const float* __restrict__ adj,
    const float* __restrict__ Wp, const float* __restrict__ bp,
    const float* __restrict__ Wr, const float* __restrict__ br,
    const float* __restrict__ Wc, const float* __restrict__ bc,
    float* __restrict__ out)
{
    // LDS budget: 3*10240 (weights) + 20480 (PT) + 2*49152 (node/edge dbuf) = 149504 B
    __shared__ alignas(16) __bf16 sWc[2 * 64 * WPITCH];   // [ks][d][32(+8 pad)] = W^T k-blocked
    __shared__ alignas(16) __bf16 sWr[2 * 64 * WPITCH];
    __shared__ alignas(16) __bf16 sWp[2 * 64 * WPITCH];
    __shared__ alignas(16) __bf16 sPT[WAVES][64 * WPITCH];// per-wave P^T[d][k(24+pad)]
    __shared__ alignas(16) float  sN[WAVES][2][ROW];      // per-wave node dbuf (XOR-8 col-swizzled)
    __shared__ alignas(16) float  sE[WAVES][2][ROW];      // per-wave edge dbuf

    const int tid = threadIdx.x;

    // ---- stage weights transposed + k-blocked, pitch 40 ----
    for (int idx = tid; idx < 4096; idx += 256) {
        int c = idx >> 6, d = idx & 63;
        int dst = (c >> 5) * (64 * WPITCH) + d * WPITCH + (c & 31);
        sWc[dst] = (__bf16)Wc[idx];
        sWr[dst] = (__bf16)Wr[idx];
        sWp[dst] = (__bf16)Wp[idx];
    }
    __syncthreads();   // the ONLY block-wide barrier

    const int lane = tid & 63;
    const int wave = tid >> 6;
    const int r    = lane & 15;
    const int g    = lane >> 4;

    __bf16* myPT = &sPT[wave][0];
    float*  nb0  = &sN[wave][0][0];
    float*  nb1  = &sN[wave][1][0];
    float*  eb0  = &sE[wave][0][0];
    float*  eb1  = &sE[wave][1][0];

    // biases straight to registers
    float bs[4], bpv[4];
    #pragma unroll
    for (int nt = 0; nt < 4; ++nt) {
        bs[nt]  = bc[nt * 16 + r] + br[nt * 16 + r];
        bpv[nt] = bp[nt * 16 + r];
    }

    const int  row1s  = (16 + r < JJ) ? (16 + r) : r;   // dup row for j>=24 tail
    const bool adjval = (g < 3);

    // ---- stage one batch's node+edge into LDS (12 x global_load_lds dwordx4) ----
    // LDS is linear; global SOURCE is XOR-8 pre-swizzled on 16B granules (involution):
    // content at LDS dword o = global[row(o)*64 + ((c4(o)^ (row&7))*4 + e)]
    auto STAGE = [&](int b, float* tn, float* te) {
        const float* nf = node + (size_t)b * ROW;
        const float* ef = edge + (size_t)b * ROW;
        #pragma unroll
        for (int m = 0; m < 6; ++m) {
            const int o   = m * 256 + lane * 4;
            const int row = o >> 6;
            const int c4  = (o & 63) >> 2;
            const int src = (row << 6) | ((c4 ^ (row & 7)) << 2);
            gld16(nf + src, tn + m * 256);
            gld16(ef + src, te + m * 256);
        }
    };

    auto LOADADJ = [&](float (&A)[2][8], int b) {
        const float* af = adj + (size_t)b * (JJ * JJ);
        #pragma unroll
        for (int mt = 0; mt < 2; ++mt) {
            const int j = mt * 16 + r;
            const bool v = adjval && (j < JJ);
            #pragma unroll
            for (int e = 0; e < 8; ++e)
                A[mt][e] = af[v ? ((g * 8 + e) * JJ + j) : 0];
        }
    };

    auto COMPUTE = [&](int b, const float* bn, const float* be, float (&rawA)[2][8]) {
        // ---- A-frags from LDS (swizzled read matches swizzled stage source) ----
        bf16x8 aN[2][2], aE[2][2];
        #pragma unroll
        for (int mt = 0; mt < 2; ++mt) {
            const int row = (mt == 0) ? r : row1s;
            const int rs  = row & 7;
            const int rb  = row << 6;
            #pragma unroll
            for (int ks = 0; ks < 2; ++ks) {
                const int c40 = ks * 8 + g * 2;
                f32x4 n0 = *(const f32x4*)(bn + rb + (((c40 + 0) ^ rs) << 2));
                f32x4 n1 = *(const f32x4*)(bn + rb + (((c40 + 1) ^ rs) << 2));
                f32x4 e0 = *(const f32x4*)(be + rb + (((c40 + 0) ^ rs) << 2));
                f32x4 e1 = *(const f32x4*)(be + rb + (((c40 + 1) ^ rs) << 2));
                bf16x8 an, ae;
                #pragma unroll
                for (int e = 0; e < 4; ++e) {
                    an[e] = (__bf16)n0[e]; an[4 + e] = (__bf16)n1[e];
                    ae[e] = (__bf16)e0[e]; ae[4 + e] = (__bf16)e1[e];
                }
                aN[mt][ks] = an; aE[mt][ks] = ae;
            }
        }
        bf16x8 aA[2];
        #pragma unroll
        for (int mt = 0; mt < 2; ++mt) {
            const int j = mt * 16 + r;
            const float m = (adjval && (j < JJ)) ? 1.0f : 0.0f;  // multiplier must be 0 in pads
            bf16x8 t;
            #pragma unroll
            for (int e = 0; e < 8; ++e) t[e] = (__bf16)(rawA[mt][e] * m);
            aA[mt] = t;
        }

        // ---- children + recurrent ----
        f32x4 accCR[2][4];
        #pragma unroll
        for (int mt = 0; mt < 2; ++mt)
            #pragma unroll
            for (int nt = 0; nt < 4; ++nt) accCR[mt][nt] = f32x4{0.f, 0.f, 0.f, 0.f};
        #pragma unroll
        for (int ks = 0; ks < 2; ++ks) {
            #pragma unroll
            for (int nt = 0; nt < 4; ++nt) {
                bf16x8 bC = *(const bf16x8*)(sWc + ks * (64 * WPITCH) + (nt * 16 + r) * WPITCH + g * 8);
                bf16x8 bR = *(const bf16x8*)(sWr + ks * (64 * WPITCH) + (nt * 16 + r) * WPITCH + g * 8);
                #pragma unroll
                for (int mt = 0; mt < 2; ++mt) {
                    accCR[mt][nt] = MFMA16(aN[mt][ks], bC, accCR[mt][nt]);
                    accCR[mt][nt] = MFMA16(aE[mt][ks], bR, accCR[mt][nt]);
                }
            }
        }

        // ---- parent projection ----
        f32x4 accP[2][4];
        #pragma unroll
        for (int mt = 0; mt < 2; ++mt)
            #pragma unroll
            for (int nt = 0; nt < 4; ++nt) accP[mt][nt] = f32x4{0.f, 0.f, 0.f, 0.f};
        #pragma unroll
        for (int ks = 0; ks < 2; ++ks) {
            #pragma unroll
            for (int nt = 0; nt < 4; ++nt) {
                bf16x8 bW = *(const bf16x8*)(sWp + ks * (64 * WPITCH) + (nt * 16 + r) * WPITCH + g * 8);
                #pragma unroll
                for (int mt = 0; mt < 2; ++mt)
                    accP[mt][nt] = MFMA16(aN[mt][ks], bW, accP[mt][nt]);
            }
        }

        // ---- P (+b_parent on real rows) -> wave-private PT[d][k], pitch 40 ----
        #pragma unroll
        for (int mt = 0; mt < 2; ++mt) {
            const bool addb = (mt == 0) || (g < 2);   // j = mt*16+g*4+rr < 24
            #pragma unroll
            for (int nt = 0; nt < 4; ++nt) {
                us4 w;
                #pragma unroll
                for (int rr = 0; rr < 4; ++rr) {
                    float v = accP[mt][nt][rr];
                    if (addb) v += bpv[nt];
                    w[rr] = __builtin_bit_cast(unsigned short, (__bf16)v);
                }
                *(us4*)(myPT + (nt * 16 + r) * WPITCH + mt * 16 + g * 4) = w;
            }
        }

        // ---- aggregation on top of accCR (MFMA C-in) ----
        f32x4 accA[2][4];
        #pragma unroll
        for (int nt = 0; nt < 4; ++nt) {
            bf16x8 bP = *(const bf16x8*)(myPT + (nt * 16 + r) * WPITCH + g * 8);
            #pragma unroll
            for (int mt = 0; mt < 2; ++mt)
                accA[mt][nt] = MFMA16(aA[mt], bP, accCR[mt][nt]);
        }

        // ---- epilogue: sigmoid((sum + b_child + b_rec)/3) ----
        #pragma unroll
        for (int mt = 0; mt < 2; ++mt) {
            #pragma unroll
            for (int rr = 0; rr < 4; ++rr) {
                const int j = mt * 16 + g * 4 + rr;
                if (j < JJ) {
                    float* op = out + (size_t)b * ROW + j * CC + r;
                    #pragma unroll
                    for (int nt = 0; nt < 4; ++nt) {
                        float x = (accA[mt][nt][rr] + bs[nt]) * (1.0f / 3.0f);
                        float s = __builtin_amdgcn_rcpf(1.0f + __expf(-x));
                        op[nt * 16] = s;
                    }
                }
            }
        }
    };

    // ---------------- counted-vmcnt pipeline, barrier-free ----------------
    const int wb = (blockIdx.x * WAVES + wave) * BPW;
    float adjCur[2][8], adjNxt[2][8];

    STAGE(wb, nb0, eb0);
    LOADADJ(adjNxt, wb);

    #pragma unroll 1
    for (int it = 0; it < BPW; ++it) {
        const int  b   = wb + it;
        const bool pre = (it + 1 < BPW);
        float* tn = (it & 1) ? nb0 : nb1;          // stage target = other half
        float* te = (it & 1) ? eb0 : eb1;
        const float* bn = (it & 1) ? nb1 : nb0;    // compute source
        const float* be = (it & 1) ? eb1 : eb0;

        if (pre) STAGE(b + 1, tn, te);
        #pragma unroll
        for (int mt = 0; mt < 2; ++mt)
            #pragma unroll
            for (int e = 0; e < 8; ++e) adjCur[mt][e] = adjNxt[mt][e];
        if (pre) LOADADJ(adjNxt, b + 1);

        // batch b's 12 gld_lds (+16 adj) were issued last iteration; leave the 28
        // just-issued ops of batch b+1 in flight across this compute phase.
        if (pre) asm volatile("s_waitcnt vmcnt(28)" ::: "memory");
        else     asm volatile("s_waitcnt vmcnt(0)"  ::: "memory");
        __builtin_amdgcn_sched_barrier(0);

        COMPUTE(b, bn, be, adjCur);
    }
}

extern "C" void kernel_launch(void* const* d_in, const int* in_sizes, int n_in,
                              void* d_out, int out_size, void* d_ws, size_t ws_size,
                              hipStream_t stream) {
    const float* node = (const float*)d_in[0];
    const float* edge = (const float*)d_in[1];
    const float* adj  = (const float*)d_in[2];
    const float* Wp   = (const float*)d_in[3];
    const float* bpar = (const float*)d_in[4];
    const float* Wr   = (const float*)d_in[5];
    const float* brec = (const float*)d_in[6];
    const float* Wc   = (const float*)d_in[7];
    const float* bch  = (const float*)d_in[8];

    n2e_kernel<<<BLOCKS, 256, 0, stream>>>(node, edge, adj, Wp, bpar, Wr, brec, Wc, bch,
                                           (float*)d_out);
}

// Round 7
// 85.963 us; speedup vs baseline: 1.2471x; 1.2471x over previous
//
#include <hip/hip_runtime.h>
#include <hip/hip_bf16.h>

typedef __bf16 bf16x8 __attribute__((ext_vector_type(8)));
typedef float  f32x4  __attribute__((ext_vector_type(4)));
typedef float  f32x8  __attribute__((ext_vector_type(8)));
typedef unsigned int u32;
typedef u32 u32x4 __attribute__((ext_vector_type(4)));

#define MFMA16(a, b, c) __builtin_amdgcn_mfma_f32_16x16x32_bf16((a), (b), (c), 0, 0, 0)

constexpr int JJ     = 24;
constexpr int CC     = 64;
constexpr int ROW    = JJ * CC;    // 1536
constexpr int WAVES  = 8;          // 512 threads/block
constexpr int BPW    = 2;
constexpr int BLOCKS = 16384 / (WAVES * BPW);   // 1024
constexpr int WP     = 40;         // weight pitch (bf16): 80B rows -> 2-way banks (free)
constexpr float SCALE = 1.0f / 3.0f;  // mean-divisor folded into weights & biases

// pack two f32 -> one dword of 2 bf16 via compiler casts (RNE, guaranteed semantics)
__device__ __forceinline__ u32 pack_bf16(float lo, float hi) {
    u32 a = (u32)__builtin_bit_cast(unsigned short, (__bf16)lo);
    u32 b = (u32)__builtin_bit_cast(unsigned short, (__bf16)hi);
    return a | (b << 16);
}

__global__ __launch_bounds__(512, 2) void n2e_kernel(
    const float* __restrict__ node, const float* __restrict__ edge,
    const float* __restrict__ adj,
    const float* __restrict__ Wp, const float* __restrict__ bp,
    const float* __restrict__ Wr, const float* __restrict__ br,
    const float* __restrict__ Wc, const float* __restrict__ bc,
    float* __restrict__ out)
{
    // LDS = weights only: 3 * 10240 B = 30720 B
    __shared__ __bf16 sWc[2 * 64 * WP];   // [ks][d][32(+8 pad)] = (W^T * 1/3) k-blocked
    __shared__ __bf16 sWr[2 * 64 * WP];
    __shared__ __bf16 sWp[2 * 64 * WP];

    const int tid = threadIdx.x;
    for (int idx = tid; idx < 4096; idx += 512) {
        int c = idx >> 6, d = idx & 63;
        int dst = (c >> 5) * (64 * WP) + d * WP + (c & 31);
        sWc[dst] = (__bf16)(Wc[idx] * SCALE);
        sWr[dst] = (__bf16)(Wr[idx] * SCALE);
        sWp[dst] = (__bf16)(Wp[idx] * SCALE);
    }
    __syncthreads();   // the ONLY barrier

    const int lane = tid & 63;
    const int wave = tid >> 6;
    const int r    = lane & 15;
    const int g    = lane >> 4;

    // biases (scaled) straight to registers; folded into MFMA C-init
    float bs[4], bpv[4];
    #pragma unroll
    for (int nt = 0; nt < 4; ++nt) {
        int i   = nt * 16 + r;
        bs[nt]  = (bc[i] + br[i]) * SCALE;
        bpv[nt] = bp[i] * SCALE;
    }

    // bpermute byte-indices for the accP(C-frag) -> bP(B-frag) redistribution:
    // bP lane(r,g)[e] = P[k=g*8+e][nt*16+r] lives at lane (g&1)*32 + (e>=4)*16 + r,
    // slot accP[(g*8+e)>>4][nt][e&3].
    const int  idx_lo = ((((g & 1) << 5) | r) << 2);
    const int  idx_hi = idx_lo + 64;
    const bool gsel   = (g >= 2);     // mt_src = 1 for k>=16
    const bool gpad   = (g == 3);     // k>=24: force bP to 0 (paranoia vs 0*Inf)

    const int  row1s  = (16 + r < JJ) ? (16 + r) : r;  // dup row for j>=24 tail
    const bool adjval = (g < 3);                       // k = g*8+e < 24 only for g<3

    for (int it = 0; it < BPW; ++it) {
        const int b = blockIdx.x * (WAVES * BPW) + wave * BPW + it;
        const float* nf = node + (size_t)b * ROW;
        const float* ef = edge + (size_t)b * ROW;
        const float* af = adj  + (size_t)b * (JJ * JJ);

        // ---- node/edge A-frags (dup rows for tail; downstream-masked) ----
        bf16x8 aN[2][2], aE[2][2];
        #pragma unroll
        for (int mt = 0; mt < 2; ++mt) {
            const int row = (mt == 0) ? r : row1s;
            #pragma unroll
            for (int ks = 0; ks < 2; ++ks) {
                f32x8 x = *(const f32x8*)(nf + row * CC + ks * 32 + g * 8);
                f32x8 y = *(const f32x8*)(ef + row * CC + ks * 32 + g * 8);
                bf16x8 an, ae;
                #pragma unroll
                for (int e = 0; e < 8; ++e) { an[e] = (__bf16)x[e]; ae[e] = (__bf16)y[e]; }
                aN[mt][ks] = an; aE[mt][ks] = ae;
            }
        }

        // ---- adj^T A-frags from global gather; multiplier zeroed in all pad slots ----
        bf16x8 aA[2];
        #pragma unroll
        for (int mt = 0; mt < 2; ++mt) {
            const int j = mt * 16 + r;
            const bool v = adjval && (j < JJ);
            const float m = v ? 1.0f : 0.0f;
            bf16x8 t;
            #pragma unroll
            for (int e = 0; e < 8; ++e)
                t[e] = (__bf16)(af[v ? ((g * 8 + e) * JJ + j) : 0] * m);
            aA[mt] = t;
        }

        // ---- children + recurrent (bias-initialized accumulators) ----
        f32x4 accCR[2][4];
        #pragma unroll
        for (int mt = 0; mt < 2; ++mt)
            #pragma unroll
            for (int nt = 0; nt < 4; ++nt)
                accCR[mt][nt] = f32x4{bs[nt], bs[nt], bs[nt], bs[nt]};
        #pragma unroll
        for (int ks = 0; ks < 2; ++ks) {
            #pragma unroll
            for (int nt = 0; nt < 4; ++nt) {
                bf16x8 bC = *(const bf16x8*)(sWc + ks * (64 * WP) + (nt * 16 + r) * WP + g * 8);
                bf16x8 bR = *(const bf16x8*)(sWr + ks * (64 * WP) + (nt * 16 + r) * WP + g * 8);
                #pragma unroll
                for (int mt = 0; mt < 2; ++mt) {
                    accCR[mt][nt] = MFMA16(aN[mt][ks], bC, accCR[mt][nt]);
                    accCR[mt][nt] = MFMA16(aE[mt][ks], bR, accCR[mt][nt]);
                }
            }
        }

        // ---- parent projection (b_parent-initialized; pad rows harmless) ----
        f32x4 accP[2][4];
        #pragma unroll
        for (int mt = 0; mt < 2; ++mt)
            #pragma unroll
            for (int nt = 0; nt < 4; ++nt)
                accP[mt][nt] = f32x4{bpv[nt], bpv[nt], bpv[nt], bpv[nt]};
        #pragma unroll
        for (int ks = 0; ks < 2; ++ks) {
            #pragma unroll
            for (int nt = 0; nt < 4; ++nt) {
                bf16x8 bW = *(const bf16x8*)(sWp + ks * (64 * WP) + (nt * 16 + r) * WP + g * 8);
                #pragma unroll
                for (int mt = 0; mt < 2; ++mt)
                    accP[mt][nt] = MFMA16(aN[mt][ks], bW, accP[mt][nt]);
            }
        }

        // ---- in-register redistribution accP -> bP + aggregation (MFMA C-in = accCR) ----
        f32x4 accA[2][4];
        #pragma unroll
        for (int nt = 0; nt < 4; ++nt) {
            u32 m0a = pack_bf16(accP[0][nt][0], accP[0][nt][1]);
            u32 m0b = pack_bf16(accP[0][nt][2], accP[0][nt][3]);
            u32 m1a = pack_bf16(accP[1][nt][0], accP[1][nt][1]);
            u32 m1b = pack_bf16(accP[1][nt][2], accP[1][nt][3]);
            u32 q0  = (u32)__builtin_amdgcn_ds_bpermute(idx_lo, (int)m0a);
            u32 q0m = (u32)__builtin_amdgcn_ds_bpermute(idx_lo, (int)m1a);
            u32 q1  = (u32)__builtin_amdgcn_ds_bpermute(idx_lo, (int)m0b);
            u32 q1m = (u32)__builtin_amdgcn_ds_bpermute(idx_lo, (int)m1b);
            u32 q2  = (u32)__builtin_amdgcn_ds_bpermute(idx_hi, (int)m0a);
            u32 q2m = (u32)__builtin_amdgcn_ds_bpermute(idx_hi, (int)m1a);
            u32 q3  = (u32)__builtin_amdgcn_ds_bpermute(idx_hi, (int)m0b);
            u32 q3m = (u32)__builtin_amdgcn_ds_bpermute(idx_hi, (int)m1b);
            u32x4 wv;
            wv[0] = gpad ? 0u : (gsel ? q0m : q0);
            wv[1] = gpad ? 0u : (gsel ? q1m : q1);
            wv[2] = gpad ? 0u : (gsel ? q2m : q2);
            wv[3] = gpad ? 0u : (gsel ? q3m : q3);
            bf16x8 bP = __builtin_bit_cast(bf16x8, wv);
            #pragma unroll
            for (int mt = 0; mt < 2; ++mt)
                accA[mt][nt] = MFMA16(aA[mt], bP, accCR[mt][nt]);
        }

        // ---- epilogue: out = sigmoid(accA) (1/3 and biases already folded) ----
        #pragma unroll
        for (int mt = 0; mt < 2; ++mt) {
            #pragma unroll
            for (int rr = 0; rr < 4; ++rr) {
                const int j = mt * 16 + g * 4 + rr;
                if (j < JJ) {
                    float* op = out + (size_t)b * ROW + j * CC + r;
                    #pragma unroll
                    for (int nt = 0; nt < 4; ++nt) {
                        float x = accA[mt][nt][rr];
                        float s = __builtin_amdgcn_rcpf(1.0f + __expf(-x));
                        op[nt * 16] = s;
                    }
                }
            }
        }
    }
}

extern "C" void kernel_launch(void* const* d_in, const int* in_sizes, int n_in,
                              void* d_out, int out_size, void* d_ws, size_t ws_size,
                              hipStream_t stream) {
    const float* node = (const float*)d_in[0];
    const float* edge = (const float*)d_in[1];
    const float* adj  = (const float*)d_in[2];
    const float* Wp   = (const float*)d_in[3];
    const float* bpar = (const float*)d_in[4];
    const float* Wr   = (const float*)d_in[5];
    const float* brec = (const float*)d_in[6];
    const float* Wc   = (const float*)d_in[7];
    const float* bch  = (const float*)d_in[8];

    n2e_kernel<<<BLOCKS, 512, 0, stream>>>(node, edge, adj, Wp, bpar, Wr, brec, Wc, bch,
                                           (float*)d_out);
}